// Round 4
// baseline (511.447 us; speedup 1.0000x reference)
//
#include <hip/hip_runtime.h>

#define P_TOT 1482625
#define BATCH 64
#define EMB 16
#define DFEAT 512
#define KCODE 512

typedef float f4 __attribute__((ext_vector_type(4)));

// ---------------------------------------------------------------------------
// Kernel 1: encoder fc + VQ argmin + quantized + per-batch loss partial (fp32).
// grid = 64 blocks (one per batch row), 256 threads.  (~3 us, off critical path)
// ---------------------------------------------------------------------------
__global__ __launch_bounds__(256) void k_embed_vq(
    const float* __restrict__ feat,
    const float* __restrict__ fcw,
    const float* __restrict__ fcb,
    const float* __restrict__ cb,
    float* __restrict__ qws,
    float* __restrict__ loss_part)
{
    const int b   = blockIdx.x;
    const int tid = threadIdx.x;

    __shared__ float red[EMB][17];
    __shared__ float embed_s[EMB];
    __shared__ float dist_s[256];
    __shared__ int   idx_s[256];

    {
        const int e = tid >> 4;       // 0..15
        const int c = tid & 15;       // chunk of 32 floats
        const float4* fp = (const float4*)(feat + b * DFEAT + c * 32);
        const float4* wp = (const float4*)(fcw  + e * DFEAT + c * 32);
        float acc = 0.f;
#pragma unroll
        for (int j = 0; j < 8; j++) {
            float4 f = fp[j], w = wp[j];
            acc += f.x * w.x + f.y * w.y + f.z * w.z + f.w * w.w;
        }
        red[e][c] = acc;
    }
    __syncthreads();
    if (tid < EMB) {
        float s = fcb[tid];
#pragma unroll
        for (int c = 0; c < 16; c++) s += red[tid][c];
        embed_s[tid] = s;
    }
    __syncthreads();

    float emb[EMB];
#pragma unroll
    for (int e = 0; e < EMB; e++) emb[e] = embed_s[e];

    float bestd = 1e30f;
    int   bestk = 0;
#pragma unroll
    for (int r = 0; r < 2; r++) {
        const int k = tid + r * 256;
        const float4* cp = (const float4*)(cb + k * EMB);
        float d = 0.f;
#pragma unroll
        for (int q = 0; q < 4; q++) {
            float4 cv = cp[q];
            d += cv.x * cv.x - 2.f * cv.x * emb[q * 4 + 0];
            d += cv.y * cv.y - 2.f * cv.y * emb[q * 4 + 1];
            d += cv.z * cv.z - 2.f * cv.z * emb[q * 4 + 2];
            d += cv.w * cv.w - 2.f * cv.w * emb[q * 4 + 3];
        }
        if (d < bestd) { bestd = d; bestk = k; }  // strict < => first-min kept
    }
    dist_s[tid] = bestd;
    idx_s[tid]  = bestk;
    __syncthreads();

    for (int s = 128; s > 0; s >>= 1) {
        if (tid < s) {
            float od = dist_s[tid + s];
            int   ok = idx_s[tid + s];
            if (od < dist_s[tid] || (od == dist_s[tid] && ok < idx_s[tid])) {
                dist_s[tid] = od;
                idx_s[tid]  = ok;
            }
        }
        __syncthreads();
    }

    if (tid == 0) {
        const int kb = idx_s[0];
        float l = 0.f;
#pragma unroll
        for (int e = 0; e < EMB; e++) {
            float qv = cb[kb * EMB + e];
            qws[b * EMB + e] = qv;        // forward(quantized_st) == quantized
            float dd = qv - embed_s[e];
            l += dd * dd;
        }
        loss_part[b] = l;
    }
}

// ---------------------------------------------------------------------------
// Edge-cleanup tables: per parity class R, the columns not covered by the
// aligned float4 windows (left [0,S_R) and right [S_R+4*N_R, P_TOT)).
// 12 (class,col) pairs x 16 rows = 192 elements total.
// ---------------------------------------------------------------------------
__device__ const int g_pcls[12] = {0, 1,1,1,1,1, 2,2,2,2,2, 3};
__device__ const int g_pcol[12] = {1482624,
                                   0, 1, 2, 1482623, 1482624,
                                   0, 1, 1482622, 1482623, 1482624,
                                   0};

// ---------------------------------------------------------------------------
// Kernel 2 (x4 classes): gen = quantized @ Wgen with ALIGNED float4 stores.
// THEORY (r4): all prior variants used dword (4B/lane) stores because P_TOT
// odd => row bases never 16B-aligned; store-side MLP at 1/4 bytes per
// outstanding-request slot explains the stuck 2.0 TB/s (vs 6.26 the fill
// achieves). Since P_TOT == 1 (mod 4): (b*P_TOT+col) % 4 == 0 iff
// col == -b (mod 4). Class-R blocks handle rows b==R (mod 4) with column
// windows shifted by S_R=(-R)&3 -> every store is a natural float4
// (1KB/wave-instr, 4x bytes per VMEM slot, 4x fewer store instrs).
// Wgen read 4x (once per class) -> L3-absorbed (95MB < 256MB).
// Loads: 2 aligned float4 per e-row + static component select (template<R>
// makes all shifts compile-time; no runtime-indexed registers).
// ---------------------------------------------------------------------------
template<int R>
__global__ __launch_bounds__(256) void k_gen_cls(
    const float* __restrict__ Wgen,
    const float* __restrict__ qws,
    const float* __restrict__ loss_part,
    float* __restrict__ out)
{
    constexpr int SR = (4 - R) & 3;                       // window shift
    constexpr long long NR = ((long long)P_TOT - SR) / 4; // float4 slots

    int bid = blockIdx.x;
    if (R == 0) {
        if (bid == 0) {
            // loss finalize + 192-element edge cleanup
            const int tid = threadIdx.x;
            if (tid < 64) {
                float v = loss_part[tid];
#pragma unroll
                for (int o = 32; o > 0; o >>= 1) v += __shfl_down(v, o, 64);
                if (tid == 0)
                    out[(size_t)BATCH * P_TOT] = 1.25f * v * (1.0f / 1024.0f);
            } else if (tid < 64 + 192) {
                const int idx = tid - 64;
                const int p = idx >> 4, u = idx & 15;
                const int b = g_pcls[p] + 4 * u;
                const size_t col = (size_t)g_pcol[p];
                float a = 0.f;
#pragma unroll
                for (int e = 0; e < EMB; e++)
                    a = fmaf(qws[b * EMB + e], Wgen[(size_t)e * P_TOT + col], a);
                out[(size_t)b * P_TOT + col] = a;
            }
            return;
        }
        bid -= 1;
    }

    const long long slot = (long long)bid * 256 + threadIdx.x;
    if (slot >= NR) return;
    const size_t S = (size_t)SR + 4 * (size_t)slot;       // first column

    // Load w[e][0..3] = Wgen[e][S..S+3] via aligned float4(s).
    // For row e the 16B-aligned columns are those with (e+col)%4==0;
    // m = (e+SR)&3 is the offset of S within its aligned block (compile-time
    // after unroll). m>0 -> read two aligned float4 and select statically.
    // Underreads (S-m) land in the previous row's tail for e>=1 (in-bounds,
    // discarded); e==0 always has m==SR <= S. Overread beyond row end only
    // possible at slot==NR-1, which takes the scalar path.
    float w[EMB][4];
    if (slot != NR - 1) {
#pragma unroll
        for (int e = 0; e < EMB; e++) {
            const int m = (e + SR) & 3;
            const float* rowp = Wgen + (size_t)e * P_TOT + (S - (size_t)m);
            f4 lo = *(const f4*)rowp;
            f4 hi = {0.f, 0.f, 0.f, 0.f};
            if (m) hi = *(const f4*)(rowp + 4);
#pragma unroll
            for (int c = 0; c < 4; c++)
                w[e][c] = (m + c < 4) ? lo[m + c] : hi[m + c - 4];
        }
    } else {
#pragma unroll
        for (int e = 0; e < EMB; e++)
#pragma unroll
            for (int c = 0; c < 4; c++)
                w[e][c] = Wgen[(size_t)e * P_TOT + S + c];
    }

    // 16 rows of this class: b = R, R+4, ..., R+60.
    // q loads are wave-uniform -> s_load/SGPR; prefetch next row's q under
    // the current row's FMA block (round-2's verified +8us pattern).
    float qn[EMB];
#pragma unroll
    for (int e = 0; e < EMB; e++) qn[e] = qws[R * EMB + e];

#pragma unroll 2
    for (int u = 0; u < 16; u++) {
        const int b = R + 4 * u;
        float qc[EMB];
#pragma unroll
        for (int e = 0; e < EMB; e++) qc[e] = qn[e];
        if (u + 1 < 16) {
            const float* q1 = qws + (b + 4) * EMB;
#pragma unroll
            for (int e = 0; e < EMB; e++) qn[e] = q1[e];
        }

        f4 acc = {0.f, 0.f, 0.f, 0.f};
#pragma unroll
        for (int e = 0; e < EMB; e++) {
            const float qe = qc[e];
            acc[0] = fmaf(qe, w[e][0], acc[0]);
            acc[1] = fmaf(qe, w[e][1], acc[1]);
            acc[2] = fmaf(qe, w[e][2], acc[2]);
            acc[3] = fmaf(qe, w[e][3], acc[3]);
        }
        // (b*P_TOT + S) % 4 == (R + SR) % 4 == 0  -> 16B-aligned store
        *(f4*)(out + (size_t)b * P_TOT + S) = acc;
    }
}

extern "C" void kernel_launch(void* const* d_in, const int* in_sizes, int n_in,
                              void* d_out, int out_size, void* d_ws, size_t ws_size,
                              hipStream_t stream) {
    const float* feat = (const float*)d_in[0];
    const float* fcw  = (const float*)d_in[1];
    const float* fcb  = (const float*)d_in[2];
    const float* cb   = (const float*)d_in[3];
    const float* wgen = (const float*)d_in[4];
    float* out = (float*)d_out;

    float* qws   = (float*)d_ws;          // 1024 fp32
    float* lpart = qws + BATCH * EMB;     // 64 fp32

    k_embed_vq<<<BATCH, 256, 0, stream>>>(feat, fcw, fcb, cb, qws, lpart);

    // slots per class: R0/R3 = 370656, R1/R2 = 370655 -> 1448 blocks each.
    // class 0 gets one extra block (blockIdx 0) for loss + edge cleanup.
    k_gen_cls<0><<<1449, 256, 0, stream>>>(wgen, qws, lpart, out);
    k_gen_cls<1><<<1448, 256, 0, stream>>>(wgen, qws, lpart, out);
    k_gen_cls<2><<<1448, 256, 0, stream>>>(wgen, qws, lpart, out);
    k_gen_cls<3><<<1448, 256, 0, stream>>>(wgen, qws, lpart, out);
}

// Round 5
// 474.352 us; speedup vs baseline: 1.0782x; 1.0782x over previous
//
#include <hip/hip_runtime.h>

#define P_TOT 1482625
#define BATCH 64
#define EMB 16
#define DFEAT 512
#define KCODE 512

// ---------------------------------------------------------------------------
// REVERT to round-2 (best: 474 us). Model fitted over 5 rounds:
//   dur_us ~= fill(240, harness, at HBM ceiling)
//           + k_embed(3) + k_gen(~76, BW-bound: 380MB write + 95MB Wgen read)
//           + ~153 (harness reset memsets/gaps, kernel-uncontrollable)
// Evidence: r4's 4x-Wgen-fetch variant moved dur by +37us ~= the +45us
// traffic model (k_gen is BW-bound); store width (r4), store grouping (r3),
// occupancy/width (r1) all null or traffic-explained.
// ---------------------------------------------------------------------------

// Kernel 1: encoder fc + VQ argmin + quantized + per-batch loss partial.
__global__ __launch_bounds__(256) void k_embed_vq(
    const float* __restrict__ feat,
    const float* __restrict__ fcw,
    const float* __restrict__ fcb,
    const float* __restrict__ cb,
    float* __restrict__ qws,
    float* __restrict__ loss_part)
{
    const int b   = blockIdx.x;
    const int tid = threadIdx.x;

    __shared__ float red[EMB][17];
    __shared__ float embed_s[EMB];
    __shared__ float dist_s[256];
    __shared__ int   idx_s[256];

    {
        const int e = tid >> 4;       // 0..15
        const int c = tid & 15;       // chunk of 32 floats
        const float4* fp = (const float4*)(feat + b * DFEAT + c * 32);
        const float4* wp = (const float4*)(fcw  + e * DFEAT + c * 32);
        float acc = 0.f;
#pragma unroll
        for (int j = 0; j < 8; j++) {
            float4 f = fp[j], w = wp[j];
            acc += f.x * w.x + f.y * w.y + f.z * w.z + f.w * w.w;
        }
        red[e][c] = acc;
    }
    __syncthreads();
    if (tid < EMB) {
        float s = fcb[tid];
#pragma unroll
        for (int c = 0; c < 16; c++) s += red[tid][c];
        embed_s[tid] = s;
    }
    __syncthreads();

    float emb[EMB];
#pragma unroll
    for (int e = 0; e < EMB; e++) emb[e] = embed_s[e];

    float bestd = 1e30f;
    int   bestk = 0;
#pragma unroll
    for (int r = 0; r < 2; r++) {
        const int k = tid + r * 256;
        const float4* cp = (const float4*)(cb + k * EMB);
        float d = 0.f;
#pragma unroll
        for (int q = 0; q < 4; q++) {
            float4 cv = cp[q];
            d += cv.x * cv.x - 2.f * cv.x * emb[q * 4 + 0];
            d += cv.y * cv.y - 2.f * cv.y * emb[q * 4 + 1];
            d += cv.z * cv.z - 2.f * cv.z * emb[q * 4 + 2];
            d += cv.w * cv.w - 2.f * cv.w * emb[q * 4 + 3];
        }
        if (d < bestd) { bestd = d; bestk = k; }  // strict < => first-min kept
    }
    dist_s[tid] = bestd;
    idx_s[tid]  = bestk;
    __syncthreads();

    for (int s = 128; s > 0; s >>= 1) {
        if (tid < s) {
            float od = dist_s[tid + s];
            int   ok = idx_s[tid + s];
            if (od < dist_s[tid] || (od == dist_s[tid] && ok < idx_s[tid])) {
                dist_s[tid] = od;
                idx_s[tid]  = ok;
            }
        }
        __syncthreads();
    }

    if (tid == 0) {
        const int kb = idx_s[0];
        float l = 0.f;
#pragma unroll
        for (int e = 0; e < EMB; e++) {
            float qv = cb[kb * EMB + e];
            qws[b * EMB + e] = qv;        // forward(quantized_st) == quantized
            float dd = qv - embed_s[e];
            l += dd * dd;
        }
        loss_part[b] = l;
    }
}

// Kernel 2: gen = quantized @ Wgen ([64,16]x[16,P]) + loss finalize.
// 1024 cols/block, 4 cols/thread stride-64 (dword coalescing; full 256B
// wave-segments), q software-pipelined one b-iteration ahead.
__global__ __launch_bounds__(256) void k_gen(
    const float* __restrict__ Wgen,
    const float* __restrict__ qws,
    const float* __restrict__ loss_part,
    float* __restrict__ out)
{
    if (blockIdx.x == 0) {
        if (threadIdx.x < 64) {
            float v = loss_part[threadIdx.x];
#pragma unroll
            for (int o = 32; o > 0; o >>= 1) v += __shfl_down(v, o, 64);
            if (threadIdx.x == 0)
                out[(size_t)BATCH * P_TOT] = 1.25f * v * (1.0f / 1024.0f);
        }
        return;
    }

    const int lane = threadIdx.x & 63;
    const int wv   = threadIdx.x >> 6;
    const int myc  = wv * 256 + lane;                 // + j*64, j<4
    const size_t col0 = (size_t)(blockIdx.x - 1) * 1024;

    if (col0 + 1024 <= (size_t)P_TOT) {
        // full block: no bounds checks
        const float* wp = Wgen + col0 + myc;
        float w[EMB][4];
#pragma unroll
        for (int e = 0; e < EMB; e++) {
            const float* we = wp + (size_t)e * P_TOT;
#pragma unroll
            for (int j = 0; j < 4; j++) w[e][j] = we[j * 64];
        }

        // prefetch q for b=0 (uniform address -> s_load)
        float qn[EMB];
#pragma unroll
        for (int e = 0; e < EMB; e++) qn[e] = qws[e];

        float* op = out + col0 + myc;
#pragma unroll 2
        for (int b = 0; b < BATCH; b++) {
            float qc[EMB];
#pragma unroll
            for (int e = 0; e < EMB; e++) qc[e] = qn[e];

            if (b + 1 < BATCH) {
                const float* q1 = qws + (b + 1) * EMB;   // uniform -> s_load
#pragma unroll
                for (int e = 0; e < EMB; e++) qn[e] = q1[e];
            }

            float acc[4] = {0.f, 0.f, 0.f, 0.f};
#pragma unroll
            for (int e = 0; e < EMB; e++) {
                const float qe = qc[e];
#pragma unroll
                for (int j = 0; j < 4; j++) acc[j] = fmaf(qe, w[e][j], acc[j]);
            }
            float* ob = op + (size_t)b * P_TOT;
#pragma unroll
            for (int j = 0; j < 4; j++) ob[j * 64] = acc[j];
        }
    } else {
        // tail block: per-column guard
#pragma unroll
        for (int j = 0; j < 4; j++) {
            const size_t c = col0 + myc + (size_t)j * 64;
            if (c < (size_t)P_TOT) {
                float w1[EMB];
#pragma unroll
                for (int e = 0; e < EMB; e++)
                    w1[e] = Wgen[(size_t)e * P_TOT + c];
                for (int b = 0; b < BATCH; b++) {
                    const float* q = qws + b * EMB;
                    float a = 0.f;
#pragma unroll
                    for (int e = 0; e < EMB; e++) a = fmaf(q[e], w1[e], a);
                    out[(size_t)b * P_TOT + c] = a;
                }
            }
        }
    }
}

extern "C" void kernel_launch(void* const* d_in, const int* in_sizes, int n_in,
                              void* d_out, int out_size, void* d_ws, size_t ws_size,
                              hipStream_t stream) {
    const float* feat = (const float*)d_in[0];
    const float* fcw  = (const float*)d_in[1];
    const float* fcb  = (const float*)d_in[2];
    const float* cb   = (const float*)d_in[3];
    const float* wgen = (const float*)d_in[4];
    float* out = (float*)d_out;

    float* qws   = (float*)d_ws;          // 1024 fp32
    float* lpart = qws + BATCH * EMB;     // 64 fp32

    k_embed_vq<<<BATCH, 256, 0, stream>>>(feat, fcw, fcb, cb, qws, lpart);

    const int colblocks = (P_TOT + 1023) / 1024;      // 1448
    k_gen<<<colblocks + 1, 256, 0, stream>>>(wgen, qws, lpart, out);
}